// Round 3
// baseline (9815.959 us; speedup 1.0000x reference)
//
#include <hip/hip_runtime.h>

#define DEVI __device__ __forceinline__

// ---------------- problem constants ----------------
constexpr int B_ = 8, TE_ = 400, TD_ = 100, E_ = 128, H_ = 256;
constexpr int A_ = 612, V_ = 50000, VEXT_ = 50050;
constexpr int H4_ = 1024, H2_ = 512;

// ---------------- workspace offsets (floats) ----------------
constexpr size_t OFS_HBF  = 0;            // fwd h state dbuf [2][256][8]
constexpr size_t OFS_HBB  = 4096;         // bwd h state dbuf
constexpr size_t OFS_CT   = 8192;         // [8][512] concat(cTf,cTb)
constexpr size_t OFS_CHC  = 12288;        // [2][8][512] decoder (h|c) dbuf
constexpr size_t OFS_CTX  = 20480;        // [8][512]
constexpr size_t OFS_PG   = 32896;        // [100][8] p_gen
constexpr size_t OFS_SROW = 33696;        // [800] vocab softmax denom
constexpr size_t OFS_FLG  = 34496;        // 256 u32 barrier flags (k2f:0-31,k2b:32-63,k4:64-127)
constexpr size_t OFS_ATT  = 34752;        // [100][8][400]
constexpr size_t OFS_EO   = 354752;       // [8][400][512] enc_out
constexpr size_t OFS_OUTS = OFS_EO;       // alias: k4b reuses eo buffer (eo dead after k4)
constexpr size_t OFS_EF   = OFS_EO + (size_t)B_*TE_*H2_;   // [8][400][612]

// ---------------- d_out scratch offsets (floats) -- dead before k5a ----------------
constexpr size_t DO_GINF = 0;                                // [400][8][1024] (k2 only)
constexpr size_t DO_EGP  = 0;                                // [8][8][400] e-partials (k4; gin dead)
constexpr size_t DO_GINB = DO_GINF + (size_t)TE_*B_*H4_;     // [400][8][1024]
constexpr size_t DO_GDEC = DO_GINB + (size_t)TE_*B_*H4_;     // [100][8][1024]
constexpr size_t DO_XPRE = DO_GDEC + (size_t)TD_*B_*H4_;     // [100][8][128]
constexpr size_t DO_CTXH = DO_XPRE + (size_t)TD_*B_*E_;      // [100][8][512]
constexpr size_t DO_HCH  = DO_CTXH + (size_t)TD_*B_*H2_;     // [100][8][512] (h|c)
constexpr size_t DO_WCG  = DO_HCH + (size_t)TD_*B_*H2_;      // [512][1024]

// ---------------- helpers ----------------
#if defined(__has_builtin)
#if __has_builtin(__builtin_amdgcn_rcpf)
#define HAS_RCPF 1
#endif
#endif

DEVI float rcp_fast(float x) {
#ifdef HAS_RCPF
  return __builtin_amdgcn_rcpf(x);
#else
  return 1.0f / x;
#endif
}

DEVI float sigm(float x) { return rcp_fast(1.0f + __expf(-x)); }
DEVI float tanh_fast(float x) {
  float e = __expf(2.0f * x);
  return 1.0f - 2.0f * rcp_fast(e + 1.0f);
}

// ---- agent-coherent accesses for mutable cross-block state ----
DEVI float ld_at(const float* p) {
  unsigned u = __hip_atomic_load((const unsigned*)p, __ATOMIC_RELAXED, __HIP_MEMORY_SCOPE_AGENT);
  return __uint_as_float(u);
}
DEVI void st_at(float* p, float v) {
  __hip_atomic_store((unsigned*)p, __float_as_uint(v), __ATOMIC_RELAXED, __HIP_MEMORY_SCOPE_AGENT);
}
DEVI float2 ld2_at(const float* p) {
  unsigned long long u =
      __hip_atomic_load((const unsigned long long*)p, __ATOMIC_RELAXED, __HIP_MEMORY_SCOPE_AGENT);
  float2 r;
  r.x = __uint_as_float((unsigned)u);
  r.y = __uint_as_float((unsigned)(u >> 32));
  return r;
}

// flag-array grid barrier with s_sleep backoff (anti-storm).
// arrival = plain agent store to own slot; wait = lane i polls flag i (first ncheck only).
DEVI void flag_bar(unsigned* flags, int ncheck, int slot, unsigned ep) {
  __syncthreads();
  if (threadIdx.x == 0) {
    asm volatile("s_waitcnt vmcnt(0)" ::: "memory");
    __hip_atomic_store(&flags[slot], ep, __ATOMIC_RELAXED, __HIP_MEMORY_SCOPE_AGENT);
  }
  if ((int)threadIdx.x < ncheck) {
    while (__hip_atomic_load(&flags[threadIdx.x], __ATOMIC_RELAXED, __HIP_MEMORY_SCOPE_AGENT) < ep) {
      __builtin_amdgcn_s_sleep(2);
    }
  }
  __syncthreads();
  asm volatile("" ::: "memory");
}

// =====================================================================
// K0: Wcg[512][1024] = Wx[128:640] @ Wih_d   (fold ctx->x->gates)
// =====================================================================
__global__ __launch_bounds__(256) void k0_wcg(
    const float* __restrict__ Wx, const float* __restrict__ Wih_d, float* __restrict__ dob)
{
  __shared__ float AsT[32 * 64];
  __shared__ float Bsh[32 * 64];
  const float* Am = Wx + 128 * 128;
  float* C = dob + DO_WCG;
  const int ct = blockIdx.x, rt = blockIdx.y, tid = threadIdx.x;
  const int c0 = ct * 64, r0 = rt * 64;
  const int tx = tid & 15, ty = tid >> 4;
  float4 acc0 = make_float4(0,0,0,0), acc1 = acc0, acc2 = acc0, acc3 = acc0;
  for (int kc = 0; kc < 4; ++kc) {
#pragma unroll
    for (int i = 0; i < 2; ++i) {
      int q = tid * 2 + i;
      int r = q >> 3, kq = q & 7;
      float4 v = *(const float4*)&Am[(size_t)(r0 + r) * 128 + kc * 32 + kq * 4];
      AsT[(kq * 4 + 0) * 64 + r] = v.x; AsT[(kq * 4 + 1) * 64 + r] = v.y;
      AsT[(kq * 4 + 2) * 64 + r] = v.z; AsT[(kq * 4 + 3) * 64 + r] = v.w;
    }
#pragma unroll
    for (int i = 0; i < 2; ++i) {
      int q = tid * 2 + i;
      int kk = q >> 4, cq = q & 15;
      *(float4*)&Bsh[kk * 64 + cq * 4] =
          *(const float4*)&Wih_d[(size_t)(kc * 32 + kk) * H4_ + c0 + cq * 4];
    }
    __syncthreads();
#pragma unroll
    for (int kk = 0; kk < 32; ++kk) {
      float4 w4 = *(float4*)&Bsh[kk * 64 + tx * 4];
      const float* ar = &AsT[kk * 64 + ty * 4];
      acc0.x += ar[0]*w4.x; acc0.y += ar[0]*w4.y; acc0.z += ar[0]*w4.z; acc0.w += ar[0]*w4.w;
      acc1.x += ar[1]*w4.x; acc1.y += ar[1]*w4.y; acc1.z += ar[1]*w4.z; acc1.w += ar[1]*w4.w;
      acc2.x += ar[2]*w4.x; acc2.y += ar[2]*w4.y; acc2.z += ar[2]*w4.z; acc2.w += ar[2]*w4.w;
      acc3.x += ar[3]*w4.x; acc3.y += ar[3]*w4.y; acc3.z += ar[3]*w4.z; acc3.w += ar[3]*w4.w;
    }
    __syncthreads();
  }
  float4 r4[4] = {acc0, acc1, acc2, acc3};
#pragma unroll
  for (int i = 0; i < 4; ++i)
    *(float4*)&C[(size_t)(r0 + ty * 4 + i) * H4_ + c0 + tx * 4] = r4[i];
}

// =====================================================================
// K1: encoder embedding + input-gate precompute; zeroes h-state + flags
// =====================================================================
__global__ __launch_bounds__(256) void k1_embed_gates(
    const int* __restrict__ etok, const float* __restrict__ emb,
    const float* __restrict__ Wih_f, const float* __restrict__ b_f,
    const float* __restrict__ Wih_b, const float* __restrict__ b_b,
    float* __restrict__ gin_f, float* __restrict__ gin_b, float* __restrict__ ws)
{
  __shared__ float er[8 * 128];
  const int t = blockIdx.x, tid = threadIdx.x;
  if (t == 0) {
    for (int i = tid; i < 8192; i += 256) ws[OFS_HBF + i] = 0.0f;
    unsigned* f = (unsigned*)(ws + OFS_FLG);
    for (int i = tid; i < 256; i += 256) f[i] = 0u;
  }
  for (int i = tid; i < 1024; i += 256) {
    int b = i >> 7, e = i & 127;
    er[i] = emb[(size_t)etok[b * TE_ + t] * E_ + e];
  }
  __syncthreads();
  float bfv[4], bbv[4];
#pragma unroll
  for (int g = 0; g < 4; ++g) { bfv[g] = b_f[g * H_ + tid]; bbv[g] = b_b[g * H_ + tid]; }
  float af[32], ab[32];
#pragma unroll
  for (int i = 0; i < 32; ++i) { af[i] = bfv[i & 3]; ab[i] = bbv[i & 3]; }
  for (int e = 0; e < E_; ++e) {
    float wf[4], wb[4];
#pragma unroll
    for (int g = 0; g < 4; ++g) {
      wf[g] = Wih_f[(size_t)e * H4_ + g * H_ + tid];
      wb[g] = Wih_b[(size_t)e * H4_ + g * H_ + tid];
    }
#pragma unroll
    for (int b = 0; b < 8; ++b) {
      float x = er[b * 128 + e];
#pragma unroll
      for (int g = 0; g < 4; ++g) { af[b * 4 + g] += x * wf[g]; ab[b * 4 + g] += x * wb[g]; }
    }
  }
#pragma unroll
  for (int b = 0; b < 8; ++b)
#pragma unroll
    for (int g = 0; g < 4; ++g) {
      gin_f[((size_t)t * 8 + b) * H4_ + g * H_ + tid] = af[b * 4 + g];
      gin_b[((size_t)t * 8 + b) * H4_ + g * H_ + tid] = ab[b * 4 + g];
    }
}

// =====================================================================
// K1d: decoder precompute: xpre[t]=emb@WxE+bx, gdec[t]=xpre@Wih_d+b_d
// =====================================================================
__global__ __launch_bounds__(256) void k1d_dec_pre(
    const int* __restrict__ dtok, const float* __restrict__ emb,
    const float* __restrict__ Wx, const float* __restrict__ bx,
    const float* __restrict__ Wih_d, const float* __restrict__ b_d,
    float* __restrict__ dob)
{
  __shared__ float er[8 * 128];
  __shared__ float xl[8 * 128];
  const int t = blockIdx.x, tid = threadIdx.x;
  for (int i = tid; i < 1024; i += 256) {
    int b = i >> 7, e = i & 127;
    er[i] = emb[(size_t)dtok[b * TD_ + t] * E_ + e];
  }
  __syncthreads();
  {
    const int col = tid & 127, bh = tid >> 7;
#pragma unroll
    for (int ii = 0; ii < 4; ++ii) {
      int b = bh + (ii << 1);
      float acc = bx[col];
      for (int k = 0; k < 128; ++k) acc += er[b * 128 + k] * Wx[(size_t)k * E_ + col];
      xl[b * 128 + col] = acc;
      dob[DO_XPRE + ((size_t)t * 8 + b) * E_ + col] = acc;
    }
  }
  __syncthreads();
  float bv[4];
#pragma unroll
  for (int g = 0; g < 4; ++g) bv[g] = b_d[g * H_ + tid];
  float af[32];
#pragma unroll
  for (int i = 0; i < 32; ++i) af[i] = bv[i & 3];
  for (int e = 0; e < E_; ++e) {
    float w[4];
#pragma unroll
    for (int g = 0; g < 4; ++g) w[g] = Wih_d[(size_t)e * H4_ + g * H_ + tid];
#pragma unroll
    for (int b = 0; b < 8; ++b) {
      float x = xl[b * 128 + e];
#pragma unroll
      for (int g = 0; g < 4; ++g) af[b * 4 + g] += x * w[g];
    }
  }
#pragma unroll
  for (int b = 0; b < 8; ++b)
#pragma unroll
    for (int g = 0; g < 4; ++g)
      dob[DO_GDEC + ((size_t)t * 8 + b) * H4_ + g * H_ + tid] = af[b * 4 + g];
}

// =====================================================================
// K2: both encoder LSTM scans, sleep-poll flag barrier per direction
// =====================================================================
__global__ __launch_bounds__(256, 1) void k2_encoder_scan(
    const float* __restrict__ gin_f, const float* __restrict__ gin_b,
    const float* __restrict__ Whh_f, const float* __restrict__ Whh_b,
    float* __restrict__ ws)
{
  __shared__ float sm[4096];
  const int bid = blockIdx.x, tid = threadIdx.x;
  const int dir = bid >> 5, c0 = (bid & 31) * 8;
  const float* Whh = dir ? Whh_b : Whh_f;
  const float* gin = dir ? gin_b : gin_f;
  float* hb = ws + (dir ? OFS_HBB : OFS_HBF);
  float* cT = ws + OFS_CT;
  float* eo = ws + OFS_EO;
  unsigned* flg = (unsigned*)(ws + OFS_FLG) + (dir ? 32 : 0);
  const int slot = bid & 31;

  const int jl = tid >> 3, kg = tid & 7;
  const int gt = jl >> 3, hcl = jl & 7;
  const int jcol = gt * H_ + c0 + hcl;
  float wreg[32];
#pragma unroll
  for (int kk = 0; kk < 32; ++kk) wreg[kk] = Whh[(size_t)(kg + kk * 8) * H4_ + jcol];

  const int uhc = tid >> 3, ub = tid & 7;
  float c_reg = 0.0f;
  unsigned ep = 0;

  for (int t = 0; t < TE_; ++t) {
    const int te = dir ? (TE_ - 1 - t) : t;
    float* hrd = hb + (t & 1) * 2048;
    float* hwr = hb + ((t & 1) ^ 1) * 2048;
#pragma unroll
    for (int j = 0; j < 4; ++j) {
      float2 v = ld2_at(&hrd[tid * 8 + j * 2]);
      sm[tid * 8 + j * 2] = v.x;
      sm[tid * 8 + j * 2 + 1] = v.y;
    }
    __syncthreads();
    float acc[8] = {0, 0, 0, 0, 0, 0, 0, 0};
#pragma unroll
    for (int kk = 0; kk < 32; ++kk) {
      float w = wreg[kk];
      const float* hp = &sm[(kg + kk * 8) * 8];
#pragma unroll
      for (int b = 0; b < 8; ++b) acc[b] += hp[b] * w;
    }
    float* part = sm + 2048;
    *(float4*)&part[(jl * 8 + kg) * 8]     = make_float4(acc[0], acc[1], acc[2], acc[3]);
    *(float4*)&part[(jl * 8 + kg) * 8 + 4] = make_float4(acc[4], acc[5], acc[6], acc[7]);
    __syncthreads();
    if (tid < 64) {
      float g[4];
#pragma unroll
      for (int gg = 0; gg < 4; ++gg) {
        float s = gin[((size_t)te * 8 + ub) * H4_ + gg * H_ + c0 + uhc];
#pragma unroll
        for (int k2 = 0; k2 < 8; ++k2) s += part[((gg * 8 + uhc) * 8 + k2) * 8 + ub];
        g[gg] = s;
      }
      float ci = sigm(g[0]), cf = sigm(g[1]), cg = tanh_fast(g[2]), co = sigm(g[3]);
      c_reg = cf * c_reg + ci * cg;
      float hn = co * tanh_fast(c_reg);
      st_at(&hwr[(c0 + uhc) * 8 + ub], hn);
      eo[((size_t)ub * TE_ + te) * H2_ + dir * H_ + c0 + uhc] = hn;
      if (t == TE_ - 1) cT[ub * H2_ + dir * H_ + c0 + uhc] = c_reg;
    }
    ep++; flag_bar(flg, 32, slot, ep);
  }
}

// =====================================================================
// K3: enc_feat = enc_out(3200,512) @ Wenc_feat(512,612) + benc_feat
// =====================================================================
__global__ __launch_bounds__(256) void k3_encfeat(
    const float* __restrict__ eo, const float* __restrict__ Wef,
    const float* __restrict__ bef, float* __restrict__ ef)
{
  __shared__ float AsT[32 * 64];
  __shared__ float Wsh[32 * 64];
  const int ct = blockIdx.x, rt = blockIdx.y, tid = threadIdx.x;
  const int c0 = ct * 64, r0 = rt * 64;
  const int tx = tid & 15, ty = tid >> 4;
  float4 acc0 = make_float4(0,0,0,0), acc1 = acc0, acc2 = acc0, acc3 = acc0;
  for (int kc = 0; kc < 16; ++kc) {
#pragma unroll
    for (int i = 0; i < 2; ++i) {
      int q = tid * 2 + i;
      int r = q >> 3, kq = q & 7;
      float4 v = *(const float4*)&eo[(size_t)(r0 + r) * H2_ + kc * 32 + kq * 4];
      AsT[(kq * 4 + 0) * 64 + r] = v.x; AsT[(kq * 4 + 1) * 64 + r] = v.y;
      AsT[(kq * 4 + 2) * 64 + r] = v.z; AsT[(kq * 4 + 3) * 64 + r] = v.w;
    }
#pragma unroll
    for (int i = 0; i < 2; ++i) {
      int q = tid * 2 + i;
      int kk = q >> 4, cq = q & 15;
      int col = c0 + cq * 4;
      float4 v = make_float4(0,0,0,0);
      if (col < A_) v = *(const float4*)&Wef[(size_t)(kc * 32 + kk) * A_ + col];
      *(float4*)&Wsh[kk * 64 + cq * 4] = v;
    }
    __syncthreads();
#pragma unroll
    for (int kk = 0; kk < 32; ++kk) {
      float4 w4 = *(float4*)&Wsh[kk * 64 + tx * 4];
      const float* ar = &AsT[kk * 64 + ty * 4];
      acc0.x += ar[0]*w4.x; acc0.y += ar[0]*w4.y; acc0.z += ar[0]*w4.z; acc0.w += ar[0]*w4.w;
      acc1.x += ar[1]*w4.x; acc1.y += ar[1]*w4.y; acc1.z += ar[1]*w4.z; acc1.w += ar[1]*w4.w;
      acc2.x += ar[2]*w4.x; acc2.y += ar[2]*w4.y; acc2.z += ar[2]*w4.z; acc2.w += ar[2]*w4.w;
      acc3.x += ar[3]*w4.x; acc3.y += ar[3]*w4.y; acc3.z += ar[3]*w4.z; acc3.w += ar[3]*w4.w;
    }
    __syncthreads();
  }
  const int col = c0 + tx * 4;
  if (col < A_) {
    float4 bb = *(const float4*)&bef[col];
    float4 r4[4] = {acc0, acc1, acc2, acc3};
#pragma unroll
    for (int i = 0; i < 4; ++i) {
      int row = r0 + ty * 4 + i;
      float4 o = make_float4(r4[i].x + bb.x, r4[i].y + bb.y, r4[i].z + bb.z, r4[i].w + bb.w);
      *(float4*)&ef[(size_t)row * A_ + col] = o;
    }
  }
}

// =====================================================================
// K4: decoder loop — 64 blocks, 3 flag-barriers/step
//   A (all 64): gates + (h,c) update
//   C (64 = 8b x 8a-slices, XCD-matched): decf slice + e-partials
//   D (16: b x d-half): softmax+ctx; 48 blocks XCD-aware prefetch Wdf[t+1]
// =====================================================================
__global__ __launch_bounds__(256, 1) void k4_decoder(
    const float* __restrict__ maskp,
    const float* __restrict__ Wred, const float* __restrict__ bred,
    const float* __restrict__ Whh_d, const float* __restrict__ b_d,
    const float* __restrict__ Wdf, const float* __restrict__ bdf,
    const float* __restrict__ vvec, float* __restrict__ ws, float* __restrict__ dob)
{
  __shared__ float sm[9216];
  float* chc  = ws + OFS_CHC;
  float* ctx  = ws + OFS_CTX;
  float* att  = ws + OFS_ATT;
  const float* eo  = ws + OFS_EO;
  const float* efG = ws + OFS_EF;
  const float* hbf = ws + OFS_HBF;   // final fwd h in buffer 0 (TE even)
  const float* hbb = ws + OFS_HBB;
  const float* cT  = ws + OFS_CT;
  unsigned* flg = (unsigned*)(ws + OFS_FLG) + 64;
  const float* Wcg  = dob + DO_WCG;
  const float* gdec = dob + DO_GDEC;
  float* egp  = dob + DO_EGP;        // [8 slice][8 b][400]
  float* ctxh = dob + DO_CTXH;
  float* hch  = dob + DO_HCH;
  const int bid = blockIdx.x, tid = threadIdx.x;
  unsigned ep = 0;

  // stationary gate weights: block owns 4 h-cols x 4 gates; K=768=[ctx(512);h(256)]
  const int kg = tid & 15, jl = tid >> 4;
  const int jcol = (jl >> 2) * 256 + (bid << 2) + (jl & 3);
  float wreg[48];
#pragma unroll
  for (int kk = 0; kk < 48; ++kk) {
    int k = kg + (kk << 4);
    wreg[kk] = (k < H2_) ? Wcg[(size_t)k * H4_ + jcol]
                         : Whh_d[(size_t)(k - H2_) * H4_ + jcol];
  }
  const int uhc = tid >> 3, ub = tid & 7;   // update roles (tid<32)

  // ---------------- P0: h0/c0, ctx0=0, XCD-aware prefetch Wdf[0] ----------------
  if (bid < 32) {
    const int isC = bid >> 4;
    const int b = (bid >> 1) & 7, half = bid & 1;
    for (int i = tid; i < H2_; i += 256)
      sm[i] = isC ? cT[b * H2_ + i]
                  : (i < H_ ? hbf[i * 8 + b] : hbb[(i - H_) * 8 + b]);
    __syncthreads();
    const int col_l = tid & 127, ks = tid >> 7;
    float acc = 0.0f;
    for (int kk = 0; kk < 256; ++kk) {
      int k = ks * 256 + kk;
      acc += sm[k] * Wred[(size_t)k * H_ + half * 128 + col_l];
    }
    sm[512 + ks * 128 + col_l] = acc;
    __syncthreads();
    if (tid < 128) {
      float v2 = fmaxf(sm[512 + tid] + sm[640 + tid] + bred[half * 128 + tid], 0.0f);
      st_at(&chc[b * H2_ + isC * H_ + half * 128 + tid], v2);
    }
  } else {
    if (bid == 32)
      for (int i = tid; i < 4096; i += 256) st_at(&ctx[i], 0.0f);
    const int s = bid & 7, p = (bid - 32) >> 3;   // 8 slices x 4 k-quarters
    const int a0 = s * 76;
    const float* wp = Wdf;
    float dm = 0.0f;
    for (int i = tid; i < 128 * 80; i += 256) {
      int kk = i / 80, a = i - kk * 80;
      dm += wp[(size_t)(p * 128 + kk) * A_ + a0 + a];
    }
    asm volatile("" :: "v"(dm));
  }
  ep++; flag_bar(flg, 64, bid, ep);

  float c_reg = 0.0f;
  if (tid < 32) c_reg = ld_at(&chc[ub * H2_ + H_ + (bid << 2) + uhc]);

  // ---------------- main loop: 3 phases/step ----------------
  for (int t = 0; t < TD_; ++t) {
    const int cur = t & 1, nxt = cur ^ 1;

    // ===== A: g = gdec[t] + [ctx;h]@[Wcg;Whh_d] -> (h,c) =====
    {
#pragma unroll
      for (int i = 0; i < 12; ++i) {
        int id = tid + (i << 8);
        int b = id / 384, rp = id - b * 384;
        int r = rp << 1;
        const float* src = (r < H2_) ? &ctx[b * H2_ + r] : &chc[cur * 4096 + b * H2_ + (r - H2_)];
        float2 v = ld2_at(src);
        sm[r * 9 + b] = v.x;
        sm[(r + 1) * 9 + b] = v.y;
      }
      __syncthreads();
      float acc[8] = {0, 0, 0, 0, 0, 0, 0, 0};
#pragma unroll
      for (int kk = 0; kk < 48; ++kk) {
        float w = wreg[kk];
        const float* hp = &sm[(kg + (kk << 4)) * 9];
#pragma unroll
        for (int b = 0; b < 8; ++b) acc[b] += hp[b] * w;
      }
      float* part = sm + 6912;
      *(float4*)&part[((jl << 4) + kg) * 8]     = make_float4(acc[0], acc[1], acc[2], acc[3]);
      *(float4*)&part[((jl << 4) + kg) * 8 + 4] = make_float4(acc[4], acc[5], acc[6], acc[7]);
      __syncthreads();
      float* g_l = sm + 8960;
      if (tid < 128) {
        int jj = tid >> 3, b = tid & 7;
        int jc = (jj >> 2) * 256 + (bid << 2) + (jj & 3);
        float s = gdec[((size_t)t * 8 + b) * H4_ + jc];
#pragma unroll
        for (int k2 = 0; k2 < 16; ++k2) s += part[((jj << 4) + k2) * 8 + b];
        g_l[jj * 8 + b] = s;
      }
      __syncthreads();
      if (tid < 32) {
        float g0 = g_l[(0 + uhc) * 8 + ub], g1 = g_l[(4 + uhc) * 8 + ub],
              g2 = g_l[(8 + uhc) * 8 + ub], g3 = g_l[(12 + uhc) * 8 + ub];
        float ci = sigm(g0), cf = sigm(g1), cg = tanh_fast(g2), co = sigm(g3);
        c_reg = cf * c_reg + ci * cg;
        float hn = co * tanh_fast(c_reg);
        int hc = (bid << 2) + uhc;
        float* hb2 = &chc[nxt * 4096 + ub * H2_];
        st_at(&hb2[hc], hn);
        st_at(&hb2[H_ + hc], c_reg);
        hch[((size_t)t * 8 + ub) * H2_ + hc] = hn;
        hch[((size_t)t * 8 + ub) * H2_ + H_ + hc] = c_reg;
      }
    }
    ep++; flag_bar(flg, 64, bid, ep);

    // ===== C: decf slice + e-partials (8 b x 8 a-slices, slice==XCD) =====
    {
      const int s = bid & 7, b = bid >> 3;
      const int a0 = s * 76;
      const int w  = (s == 7) ? 80 : 76;
      float* hcl = sm;            // 512
      float* dfl = sm + 512;      // 80
      float* vvl = sm + 640;      // 80
      float* prt = sm + 768;      // 32*8
      {
        float2 v = ld2_at(&chc[nxt * 4096 + b * H2_ + (tid << 1)]);
        hcl[tid << 1] = v.x;
        hcl[(tid << 1) + 1] = v.y;
      }
      for (int i = tid; i < w; i += 256) vvl[i] = vvec[a0 + i];
      __syncthreads();
      const int a_l = tid & 31, ks = tid >> 5;          // 8 k-slices of 64
      const float* wp = Wdf + (size_t)t * H2_ * A_;
#pragma unroll
      for (int p = 0; p < 3; ++p) {
        int pa = p * 32 + a_l;
        float acc = 0.0f;
        if (pa < w) {
          const int a = a0 + pa;
#pragma unroll 8
          for (int kk = 0; kk < 64; ++kk) {
            int k = (ks << 6) + kk;
            acc += hcl[k] * wp[(size_t)k * A_ + a];
          }
        }
        prt[a_l * 8 + ks] = acc;
        __syncthreads();
        if (tid < 32 && p * 32 + tid < w) {
          float ssum = bdf[t * A_ + a0 + p * 32 + tid];
#pragma unroll
          for (int k2 = 0; k2 < 8; ++k2) ssum += prt[tid * 8 + k2];
          dfl[p * 32 + tid] = ssum;
        }
        __syncthreads();
      }
      // e-partials over own a-slice, one thread per te
      const int w4 = w >> 2;
      for (int te = tid; te < TE_; te += 256) {
        const float* efp = &efG[((size_t)b * TE_ + te) * A_ + a0];
        float acc = 0.0f;
        for (int q = 0; q < w4; ++q) {
          float4 e4 = *(const float4*)&efp[q * 4];
          acc += vvl[q * 4 + 0] * tanh_fast(e4.x + dfl[q * 4 + 0]);
          acc += vvl[q * 4 + 1] * tanh_fast(e4.y + dfl[q * 4 + 1]);
          acc += vvl[q * 4 + 2] * tanh_fast(e4.z + dfl[q * 4 + 2]);
          acc += vvl[q * 4 + 3] * tanh_fast(e4.w + dfl[q * 4 + 3]);
        }
        st_at(&egp[((size_t)s * 8 + b) * TE_ + te], acc);
      }
    }
    ep++; flag_bar(flg, 64, bid, ep);

    // ===== D: softmax + ctx (16 blocks); others prefetch Wdf[t+1] =====
    if (bid < 16) {
      const int b = bid & 7, dh = bid >> 3;
      float* eu  = sm;            // 400
      float* red = sm + 512;      // 256
      for (int te = tid; te < TE_; te += 256) {
        float s2 = 0.0f;
#pragma unroll
        for (int s3 = 0; s3 < 8; ++s3) s2 += ld_at(&egp[((size_t)s3 * 8 + b) * TE_ + te]);
        eu[te] = s2;
      }
      __syncthreads();
      float m = -3.4e38f;
      for (int i = tid; i < TE_; i += 256) m = fmaxf(m, eu[i]);
      red[tid] = m; __syncthreads();
      for (int s2 = 128; s2 > 0; s2 >>= 1) { if (tid < s2) red[tid] = fmaxf(red[tid], red[tid + s2]); __syncthreads(); }
      m = red[0]; __syncthreads();
      float sl = 0.0f;
      for (int i = tid; i < TE_; i += 256) {
        float u = __expf(eu[i] - m) * maskp[b * TE_ + i];
        eu[i] = u; sl += u;
      }
      red[tid] = sl; __syncthreads();
      for (int s2 = 128; s2 > 0; s2 >>= 1) { if (tid < s2) red[tid] += red[tid + s2]; __syncthreads(); }
      const float inv = rcp_fast(red[0]);
      const int d0 = dh * 256;
      float acc = 0.0f;
      const float* eop = &eo[(size_t)b * TE_ * H2_ + d0 + tid];
      for (int te = 0; te < TE_; ++te) acc += eu[te] * eop[(size_t)te * H2_];
      float cv = acc * inv;
      st_at(&ctx[b * H2_ + d0 + tid], cv);
      ctxh[((size_t)t * 8 + b) * H2_ + d0 + tid] = cv;
      if (dh == 0)
        for (int i = tid; i < TE_; i += 256) att[((size_t)t * 8 + b) * TE_ + i] = eu[i] * inv;
    } else if (t + 1 < TD_) {
      // XCD-aware prefetch: slice s = bid&7 lives on this block's XCD
      const int s = bid & 7, p = (bid - 16) >> 3;     // p in [0,6)
      const int a0 = s * 76;
      const int k0 = p * 86, nk = (p == 5) ? 82 : 86;
      const float* wp = Wdf + (size_t)(t + 1) * H2_ * A_;
      float dm = 0.0f;
      for (int i = tid; i < nk * 80; i += 256) {
        int kk = i / 80, a = i - kk * 80;
        dm += wp[(size_t)(k0 + kk) * A_ + a0 + a];
      }
      asm volatile("" :: "v"(dm));
    }
    ep++; flag_bar(flg, 16, bid, ep);   // only D-compute blocks gate the release
  }
}

// =====================================================================
// K4b: batched post-pass: x_t, outs_t, p_gen_t for all t (grid 100)
// =====================================================================
__global__ __launch_bounds__(256) void k4b_post(
    const float* __restrict__ Wx, const float* __restrict__ Wout, const float* __restrict__ bout,
    const float* __restrict__ Wpg, const float* __restrict__ bpg,
    float* __restrict__ ws, const float* __restrict__ dob)
{
  __shared__ float hcl[4096], ctxl[4096], cpl[4096], xl[1024], red2[256];
  const int t = blockIdx.x, tid = threadIdx.x;
  const float* hch  = dob + DO_HCH;
  const float* ctxh = dob + DO_CTXH;
  const float* xpre = dob + DO_XPRE;
  for (int i = tid; i < 4096; i += 256) {
    hcl[i]  = hch[(size_t)t * 4096 + i];
    ctxl[i] = ctxh[(size_t)t * 4096 + i];
    cpl[i]  = t ? ctxh[(size_t)(t - 1) * 4096 + i] : 0.0f;
  }
  __syncthreads();
  // x_t = xpre_t + ctx_{t-1} @ Wx[128:640]
  {
    const int col = tid & 127, bh = tid >> 7;
#pragma unroll
    for (int ii = 0; ii < 4; ++ii) {
      int b = bh + (ii << 1);
      float acc = xpre[(size_t)t * 1024 + b * E_ + col];
      for (int k = 0; k < H2_; ++k) acc += cpl[b * H2_ + k] * Wx[(size_t)(128 + k) * E_ + col];
      xl[b * E_ + col] = acc;
    }
  }
  __syncthreads();
  // outs_t = [h, ctx] @ Wout + bout
  {
    const int col = tid;
    for (int b = 0; b < 8; ++b) {
      float acc = bout[col];
      for (int k = 0; k < 768; ++k)
        acc += (k < H_ ? hcl[b * H2_ + k] : ctxl[b * H2_ + (k - H_)]) * Wout[(size_t)k * H_ + col];
      ws[OFS_OUTS + ((size_t)t * 8 + b) * H_ + col] = acc;
    }
  }
  // p_gen = sigm([ctx, h, c, x] @ Wpg + bpg)
  {
    const int b = tid >> 5, sg = tid & 31;
    float acc = 0.0f;
    for (int j = 0; j < 36; ++j) {
      int k = sg * 36 + j;
      float xv;
      if (k < H2_)       xv = ctxl[b * H2_ + k];
      else if (k < 768)  xv = hcl[b * H2_ + (k - H2_)];
      else if (k < 1024) xv = hcl[b * H2_ + H_ + (k - 768)];
      else               xv = xl[b * E_ + (k - 1024)];
      acc += xv * Wpg[k];
    }
    red2[tid] = acc;
    __syncthreads();
    if (tid < 8) {
      float s = 0.0f;
      for (int k2 = 0; k2 < 32; ++k2) s += red2[tid * 32 + k2];
      ws[OFS_PG + t * 8 + tid] = sigm(s + bpg[0]);
    }
  }
}

// =====================================================================
// K5a: logits = outs(800,256) @ Wv(256,50000) + bv -> d_out
// =====================================================================
__global__ __launch_bounds__(256) void k5a_logits(
    const float* __restrict__ outs, const float* __restrict__ Wv,
    const float* __restrict__ bv, float* __restrict__ out)
{
  __shared__ float aT[32 * 64];
  __shared__ float wl[32 * 256];
  const int ct = blockIdx.x, rt = blockIdx.y, tid = threadIdx.x;
  const int r0 = rt * 64, c0 = ct * 256;
  const int cq = tid & 63, rg = tid >> 6;
  float4 acc[16];
#pragma unroll
  for (int i = 0; i < 16; ++i) acc[i] = make_float4(0, 0, 0, 0);
  for (int kc = 0; kc < 8; ++kc) {
#pragma unroll
    for (int i = 0; i < 2; ++i) {
      int q = tid * 2 + i;
      int r = q >> 3, kq = q & 7;
      float4 v = make_float4(0, 0, 0, 0);
      if (r0 + r < 800) v = *(const float4*)&outs[(size_t)(r0 + r) * H_ + kc * 32 + kq * 4];
      aT[(kq * 4 + 0) * 64 + r] = v.x; aT[(kq * 4 + 1) * 64 + r] = v.y;
      aT[(kq * 4 + 2) * 64 + r] = v.z; aT[(kq * 4 + 3) * 64 + r] = v.w;
    }
#pragma unroll
    for (int i = 0; i < 8; ++i) {
      int q = tid + i * 256;
      int kk = q >> 6, c4 = q & 63;
      int col = c0 + c4 * 4;
      float4 v = make_float4(0, 0, 0, 0);
      if (col < V_) v = *(const float4*)&Wv[(size_t)(kc * 32 + kk) * V_ + col];
      *(float4*)&wl[kk * 256 + c4 * 4] = v;
    }
    __syncthreads();
#pragma unroll
    for (int kk = 0; kk < 32; ++kk) {
      float4 w4 = *(float4*)&wl[kk * 256 + cq * 4];
      const float* ar = &aT[kk * 64 + rg * 16];
#pragma unroll
      for (int rr = 0; rr < 16; ++rr) {
        float a = ar[rr];
        acc[rr].x += a * w4.x; acc[rr].y += a * w4.y;
        acc[rr].z += a * w4.z; acc[rr].w += a * w4.w;
      }
    }
    __syncthreads();
  }
  const int col = c0 + cq * 4;
  if (col < V_) {
    float4 bb = *(const float4*)&bv[col];
#pragma unroll
    for (int rr = 0; rr < 16; ++rr) {
      int row = r0 + rg * 16 + rr;
      if (row < 800) {
        float2 lo = make_float2(acc[rr].x + bb.x, acc[rr].y + bb.y);
        float2 hi = make_float2(acc[rr].z + bb.z, acc[rr].w + bb.w);
        *(float2*)&out[(size_t)row * VEXT_ + col] = lo;
        *(float2*)&out[(size_t)row * VEXT_ + col + 2] = hi;
      }
    }
  }
}

// K5b: per-row sum of exp(logit)
__global__ __launch_bounds__(256) void k5b_rowsum(const float* __restrict__ out, float* __restrict__ Srow)
{
  __shared__ float red[256];
  const int r = blockIdx.x, tid = threadIdx.x;
  const float* base = out + (size_t)r * VEXT_;
  float s = 0.0f;
  for (int i = tid; i < V_ / 2; i += 256) {
    float2 v = *(const float2*)&base[i * 2];
    s += __expf(v.x) + __expf(v.y);
  }
  red[tid] = s; __syncthreads();
  for (int st = 128; st > 0; st >>= 1) { if (tid < st) red[tid] += red[tid + st]; __syncthreads(); }
  if (tid == 0) Srow[r] = red[0];
}

// K5c: in-place final = pgen * exp(logit)/S ; zero OOV tail
__global__ __launch_bounds__(256) void k5c_final(
    float* __restrict__ out, const float* __restrict__ Srow, const float* __restrict__ pg)
{
  const int cc = blockIdx.x, r = blockIdx.y, tid = threadIdx.x;
  const float scale = pg[r] * rcp_fast(Srow[r]);
  float* base = out + (size_t)r * VEXT_;
#pragma unroll
  for (int i = 0; i < 4; ++i) {
    int col = cc * 2048 + i * 512 + tid * 2;
    if (col < V_) {
      float2 v = *(float2*)&base[col];
      v.x = __expf(v.x) * scale; v.y = __expf(v.y) * scale;
      *(float2*)&base[col] = v;
    } else if (col < VEXT_) {
      *(float2*)&base[col] = make_float2(0.0f, 0.0f);
    }
  }
}

// K5d: scatter copy distribution
__global__ __launch_bounds__(256) void k5d_scatter(
    float* __restrict__ out, const float* __restrict__ ws, const int* __restrict__ ext)
{
  const int r = blockIdx.x, tid = threadIdx.x;
  const int b = r & 7;
  const float* at = ws + OFS_ATT + (size_t)r * TE_;
  const float w = 1.0f - ws[OFS_PG + r];
  float* base = out + (size_t)r * VEXT_;
  for (int i = tid; i < TE_; i += 256)
    atomicAdd(&base[ext[b * TE_ + i]], w * at[i]);
}

// =====================================================================
extern "C" void kernel_launch(void* const* d_in, const int* in_sizes, int n_in,
                              void* d_out, int out_size, void* d_ws, size_t ws_size,
                              hipStream_t stream) {
  const int*   etok  = (const int*)d_in[0];
  const int*   dtok  = (const int*)d_in[1];
  const int*   ext   = (const int*)d_in[2];
  const float* maskp = (const float*)d_in[3];
  const float* emb   = (const float*)d_in[4];
  const float* Wih_f = (const float*)d_in[5];
  const float* Whh_f = (const float*)d_in[6];
  const float* b_f   = (const float*)d_in[7];
  const float* Wih_b = (const float*)d_in[8];
  const float* Whh_b = (const float*)d_in[9];
  const float* b_b   = (const float*)d_in[10];
  const float* Wred  = (const float*)d_in[11];
  const float* bred  = (const float*)d_in[12];
  const float* Wef   = (const float*)d_in[13];
  const float* bef   = (const float*)d_in[14];
  const float* vvec  = (const float*)d_in[15];
  const float* Wx    = (const float*)d_in[16];
  const float* bx    = (const float*)d_in[17];
  const float* Wih_d = (const float*)d_in[18];
  const float* Whh_d = (const float*)d_in[19];
  const float* b_d   = (const float*)d_in[20];
  const float* Wdf   = (const float*)d_in[21];
  const float* bdf   = (const float*)d_in[22];
  const float* Wpg   = (const float*)d_in[23];
  const float* bpg   = (const float*)d_in[24];
  const float* Wout  = (const float*)d_in[25];
  const float* bout  = (const float*)d_in[26];
  const float* Wv    = (const float*)d_in[27];
  const float* bv    = (const float*)d_in[28];
  float* out = (float*)d_out;
  float* wsf = (float*)d_ws;
  float* dob = out;   // d_out used as scratch until k5a overwrites it

  float* gin_f = dob + DO_GINF;
  float* gin_b = dob + DO_GINB;

  k1_embed_gates<<<400, 256, 0, stream>>>(etok, emb, Wih_f, b_f, Wih_b, b_b, gin_f, gin_b, wsf);
  k0_wcg<<<dim3(16, 8), 256, 0, stream>>>(Wx, Wih_d, dob);
  k1d_dec_pre<<<100, 256, 0, stream>>>(dtok, emb, Wx, bx, Wih_d, b_d, dob);

  {
    void* args2[5] = {(void*)&gin_f, (void*)&gin_b, (void*)&Whh_f, (void*)&Whh_b, (void*)&wsf};
    if (hipLaunchCooperativeKernel((void*)k2_encoder_scan, dim3(64), dim3(256), args2, 0, stream) != hipSuccess)
      k2_encoder_scan<<<64, 256, 0, stream>>>(gin_f, gin_b, Whh_f, Whh_b, wsf);
  }

  k3_encfeat<<<dim3(10, 50), 256, 0, stream>>>(wsf + OFS_EO, Wef, bef, wsf + OFS_EF);

  {
    void* args4[10] = {(void*)&maskp, (void*)&Wred, (void*)&bred, (void*)&Whh_d, (void*)&b_d,
                       (void*)&Wdf, (void*)&bdf, (void*)&vvec, (void*)&wsf, (void*)&dob};
    if (hipLaunchCooperativeKernel((void*)k4_decoder, dim3(64), dim3(256), args4, 0, stream) != hipSuccess)
      k4_decoder<<<64, 256, 0, stream>>>(maskp, Wred, bred, Whh_d, b_d, Wdf, bdf, vvec, wsf, dob);
  }

  k4b_post<<<100, 256, 0, stream>>>(Wx, Wout, bout, Wpg, bpg, wsf, dob);

  k5a_logits<<<dim3(196, 13), 256, 0, stream>>>(wsf + OFS_OUTS, Wv, bv, out);
  k5b_rowsum<<<800, 256, 0, stream>>>(out, wsf + OFS_SROW);
  k5c_final<<<dim3(25, 800), 256, 0, stream>>>(out, wsf + OFS_SROW, wsf + OFS_PG);
  k5d_scatter<<<800, 256, 0, stream>>>(out, wsf, ext);
}

// Round 4
// 5380.421 us; speedup vs baseline: 1.8244x; 1.8244x over previous
//
#include <hip/hip_runtime.h>

#define DEVI __device__ __forceinline__

// ---------------- problem constants ----------------
constexpr int B_ = 8, TE_ = 400, TD_ = 100, E_ = 128, H_ = 256;
constexpr int A_ = 612, V_ = 50000, VEXT_ = 50050;
constexpr int H4_ = 1024, H2_ = 512;

// ---------------- workspace offsets (floats) ----------------
constexpr size_t OFS_HBF  = 0;            // fwd h state dbuf [2][256][8]
constexpr size_t OFS_HBB  = 4096;         // bwd h state dbuf
constexpr size_t OFS_CT   = 8192;         // [8][512] concat(cTf,cTb)
constexpr size_t OFS_CHC  = 12288;        // [2][8][512] decoder (h|c) dbuf
constexpr size_t OFS_CTX  = 20480;        // [8][512]
constexpr size_t OFS_DECF = 24576;        // [8][612] (pad 5120)
constexpr size_t OFS_EG   = 29696;        // [8][400] attn logits
constexpr size_t OFS_PG   = 32896;        // [100][8] p_gen
constexpr size_t OFS_SROW = 33696;        // [800] vocab softmax denom
constexpr size_t OFS_FLG  = 34496;        // 1024 u32, slots spread 4 dwords apart
constexpr size_t OFS_ATT  = 35520;        // [100][8][400]
constexpr size_t OFS_EO   = 355520;       // [8][400][512] enc_out
constexpr size_t OFS_OUTS = OFS_EO;       // alias: k4b reuses eo buffer (eo dead after k4)
constexpr size_t OFS_EF   = OFS_EO + (size_t)B_*TE_*H2_;   // [8][400][612]

// ---------------- d_out scratch offsets (floats) -- dead before k5a ----------------
constexpr size_t DO_GINF = 0;                                // [400][8][1024]
constexpr size_t DO_GINB = DO_GINF + (size_t)TE_*B_*H4_;     // [400][8][1024]
constexpr size_t DO_GDEC = DO_GINB + (size_t)TE_*B_*H4_;     // [100][8][1024]
constexpr size_t DO_XPRE = DO_GDEC + (size_t)TD_*B_*H4_;     // [100][8][128]
constexpr size_t DO_CTXH = DO_XPRE + (size_t)TD_*B_*E_;      // [100][8][512]
constexpr size_t DO_HCH  = DO_CTXH + (size_t)TD_*B_*H2_;     // [100][8][512] (h|c)
constexpr size_t DO_WCG  = DO_HCH + (size_t)TD_*B_*H2_;      // [512][1024]

// ---------------- helpers ----------------
#if defined(__has_builtin)
#if __has_builtin(__builtin_amdgcn_rcpf)
#define HAS_RCPF 1
#endif
#endif

DEVI float rcp_fast(float x) {
#ifdef HAS_RCPF
  return __builtin_amdgcn_rcpf(x);
#else
  return 1.0f / x;
#endif
}

DEVI float sigm(float x) { return rcp_fast(1.0f + __expf(-x)); }
DEVI float tanh_fast(float x) {
  float e = __expf(2.0f * x);
  return 1.0f - 2.0f * rcp_fast(e + 1.0f);
}

// ---- agent-coherent scalar accesses (compiler-generated sc flags) ----
DEVI float ld_at(const float* p) {
  unsigned u = __hip_atomic_load((const unsigned*)p, __ATOMIC_RELAXED, __HIP_MEMORY_SCOPE_AGENT);
  return __uint_as_float(u);
}
DEVI void st_at(float* p, float v) {
  __hip_atomic_store((unsigned*)p, __float_as_uint(v), __ATOMIC_RELAXED, __HIP_MEMORY_SCOPE_AGENT);
}

#define WAIT_VM() do { asm volatile("s_waitcnt vmcnt(0)" ::: "memory"); \
                       __builtin_amdgcn_sched_barrier(0); } while (0)

// flag-array grid barrier, slots spread 16B apart, sleep backoff
DEVI void flag_bar(unsigned* flags, int ncheck, int slot, unsigned ep) {
  __syncthreads();
  if (threadIdx.x == 0) {
    asm volatile("s_waitcnt vmcnt(0)" ::: "memory");
    __hip_atomic_store(&flags[slot * 4], ep, __ATOMIC_RELAXED, __HIP_MEMORY_SCOPE_AGENT);
  }
  if ((int)threadIdx.x < ncheck) {
    while (__hip_atomic_load(&flags[threadIdx.x * 4], __ATOMIC_RELAXED, __HIP_MEMORY_SCOPE_AGENT) < ep) {
      __builtin_amdgcn_s_sleep(2);
    }
  }
  __syncthreads();
  asm volatile("" ::: "memory");
}

// =====================================================================
// K0: Wcg[512][1024] = Wx[128:640] @ Wih_d   (fold ctx->x->gates)
// =====================================================================
__global__ __launch_bounds__(256) void k0_wcg(
    const float* __restrict__ Wx, const float* __restrict__ Wih_d, float* __restrict__ dob)
{
  __shared__ float AsT[32 * 64];
  __shared__ float Bsh[32 * 64];
  const float* Am = Wx + 128 * 128;
  float* C = dob + DO_WCG;
  const int ct = blockIdx.x, rt = blockIdx.y, tid = threadIdx.x;
  const int c0 = ct * 64, r0 = rt * 64;
  const int tx = tid & 15, ty = tid >> 4;
  float4 acc0 = make_float4(0,0,0,0), acc1 = acc0, acc2 = acc0, acc3 = acc0;
  for (int kc = 0; kc < 4; ++kc) {
#pragma unroll
    for (int i = 0; i < 2; ++i) {
      int q = tid * 2 + i;
      int r = q >> 3, kq = q & 7;
      float4 v = *(const float4*)&Am[(size_t)(r0 + r) * 128 + kc * 32 + kq * 4];
      AsT[(kq * 4 + 0) * 64 + r] = v.x; AsT[(kq * 4 + 1) * 64 + r] = v.y;
      AsT[(kq * 4 + 2) * 64 + r] = v.z; AsT[(kq * 4 + 3) * 64 + r] = v.w;
    }
#pragma unroll
    for (int i = 0; i < 2; ++i) {
      int q = tid * 2 + i;
      int kk = q >> 4, cq = q & 15;
      *(float4*)&Bsh[kk * 64 + cq * 4] =
          *(const float4*)&Wih_d[(size_t)(kc * 32 + kk) * H4_ + c0 + cq * 4];
    }
    __syncthreads();
#pragma unroll
    for (int kk = 0; kk < 32; ++kk) {
      float4 w4 = *(float4*)&Bsh[kk * 64 + tx * 4];
      const float* ar = &AsT[kk * 64 + ty * 4];
      acc0.x += ar[0]*w4.x; acc0.y += ar[0]*w4.y; acc0.z += ar[0]*w4.z; acc0.w += ar[0]*w4.w;
      acc1.x += ar[1]*w4.x; acc1.y += ar[1]*w4.y; acc1.z += ar[1]*w4.z; acc1.w += ar[1]*w4.w;
      acc2.x += ar[2]*w4.x; acc2.y += ar[2]*w4.y; acc2.z += ar[2]*w4.z; acc2.w += ar[2]*w4.w;
      acc3.x += ar[3]*w4.x; acc3.y += ar[3]*w4.y; acc3.z += ar[3]*w4.z; acc3.w += ar[3]*w4.w;
    }
    __syncthreads();
  }
  float4 r4[4] = {acc0, acc1, acc2, acc3};
#pragma unroll
  for (int i = 0; i < 4; ++i)
    *(float4*)&C[(size_t)(r0 + ty * 4 + i) * H4_ + c0 + tx * 4] = r4[i];
}

// =====================================================================
// K1: encoder embedding + input-gate precompute; zeroes h-state + flags
// =====================================================================
__global__ __launch_bounds__(256) void k1_embed_gates(
    const int* __restrict__ etok, const float* __restrict__ emb,
    const float* __restrict__ Wih_f, const float* __restrict__ b_f,
    const float* __restrict__ Wih_b, const float* __restrict__ b_b,
    float* __restrict__ gin_f, float* __restrict__ gin_b, float* __restrict__ ws)
{
  __shared__ float er[8 * 128];
  const int t = blockIdx.x, tid = threadIdx.x;
  if (t == 0) {
    for (int i = tid; i < 8192; i += 256) ws[OFS_HBF + i] = 0.0f;
    unsigned* f = (unsigned*)(ws + OFS_FLG);
    for (int i = tid; i < 1024; i += 256) f[i] = 0u;
  }
  for (int i = tid; i < 1024; i += 256) {
    int b = i >> 7, e = i & 127;
    er[i] = emb[(size_t)etok[b * TE_ + t] * E_ + e];
  }
  __syncthreads();
  float bfv[4], bbv[4];
#pragma unroll
  for (int g = 0; g < 4; ++g) { bfv[g] = b_f[g * H_ + tid]; bbv[g] = b_b[g * H_ + tid]; }
  float af[32], ab[32];
#pragma unroll
  for (int i = 0; i < 32; ++i) { af[i] = bfv[i & 3]; ab[i] = bbv[i & 3]; }
  for (int e = 0; e < E_; ++e) {
    float wf[4], wb[4];
#pragma unroll
    for (int g = 0; g < 4; ++g) {
      wf[g] = Wih_f[(size_t)e * H4_ + g * H_ + tid];
      wb[g] = Wih_b[(size_t)e * H4_ + g * H_ + tid];
    }
#pragma unroll
    for (int b = 0; b < 8; ++b) {
      float x = er[b * 128 + e];
#pragma unroll
      for (int g = 0; g < 4; ++g) { af[b * 4 + g] += x * wf[g]; ab[b * 4 + g] += x * wb[g]; }
    }
  }
#pragma unroll
  for (int b = 0; b < 8; ++b)
#pragma unroll
    for (int g = 0; g < 4; ++g) {
      gin_f[((size_t)t * 8 + b) * H4_ + g * H_ + tid] = af[b * 4 + g];
      gin_b[((size_t)t * 8 + b) * H4_ + g * H_ + tid] = ab[b * 4 + g];
    }
}

// =====================================================================
// K1d: decoder precompute: xpre[t]=emb@WxE+bx, gdec[t]=xpre@Wih_d+b_d
// =====================================================================
__global__ __launch_bounds__(256) void k1d_dec_pre(
    const int* __restrict__ dtok, const float* __restrict__ emb,
    const float* __restrict__ Wx, const float* __restrict__ bx,
    const float* __restrict__ Wih_d, const float* __restrict__ b_d,
    float* __restrict__ dob)
{
  __shared__ float er[8 * 128];
  __shared__ float xl[8 * 128];
  const int t = blockIdx.x, tid = threadIdx.x;
  for (int i = tid; i < 1024; i += 256) {
    int b = i >> 7, e = i & 127;
    er[i] = emb[(size_t)dtok[b * TD_ + t] * E_ + e];
  }
  __syncthreads();
  {
    const int col = tid & 127, bh = tid >> 7;
#pragma unroll
    for (int ii = 0; ii < 4; ++ii) {
      int b = bh + (ii << 1);
      float acc = bx[col];
      for (int k = 0; k < 128; ++k) acc += er[b * 128 + k] * Wx[(size_t)k * E_ + col];
      xl[b * 128 + col] = acc;
      dob[DO_XPRE + ((size_t)t * 8 + b) * E_ + col] = acc;
    }
  }
  __syncthreads();
  float bv[4];
#pragma unroll
  for (int g = 0; g < 4; ++g) bv[g] = b_d[g * H_ + tid];
  float af[32];
#pragma unroll
  for (int i = 0; i < 32; ++i) af[i] = bv[i & 3];
  for (int e = 0; e < E_; ++e) {
    float w[4];
#pragma unroll
    for (int g = 0; g < 4; ++g) w[g] = Wih_d[(size_t)e * H4_ + g * H_ + tid];
#pragma unroll
    for (int b = 0; b < 8; ++b) {
      float x = xl[b * 128 + e];
#pragma unroll
      for (int g = 0; g < 4; ++g) af[b * 4 + g] += x * w[g];
    }
  }
#pragma unroll
  for (int b = 0; b < 8; ++b)
#pragma unroll
    for (int g = 0; g < 4; ++g)
      dob[DO_GDEC + ((size_t)t * 8 + b) * H4_ + g * H_ + tid] = af[b * 4 + g];
}

// =====================================================================
// K2: both encoder LSTM scans — batched wide coherent staging
// =====================================================================
__global__ __launch_bounds__(256, 1) void k2_encoder_scan(
    const float* __restrict__ gin_f, const float* __restrict__ gin_b,
    const float* __restrict__ Whh_f, const float* __restrict__ Whh_b,
    float* __restrict__ ws)
{
  __shared__ float sm[4096];
  const int bid = blockIdx.x, tid = threadIdx.x;
  const int dir = bid >> 5, c0 = (bid & 31) * 8;
  const float* Whh = dir ? Whh_b : Whh_f;
  const float* gin = dir ? gin_b : gin_f;
  float* hb = ws + (dir ? OFS_HBB : OFS_HBF);
  float* cT = ws + OFS_CT;
  float* eo = ws + OFS_EO;
  unsigned* flg = (unsigned*)(ws + OFS_FLG) + (dir ? 128 : 0);
  const int slot = bid & 31;

  const int jl = tid >> 3, kg = tid & 7;
  const int gt = jl >> 3, hcl = jl & 7;
  const int jcol = gt * H_ + c0 + hcl;
  float wreg[32];
#pragma unroll
  for (int kk = 0; kk < 32; ++kk) wreg[kk] = Whh[(size_t)(kg + kk * 8) * H4_ + jcol];

  const int uhc = tid >> 3, ub = tid & 7;
  float c_reg = 0.0f;
  unsigned ep = 0;

  for (int t = 0; t < TE_; ++t) {
    const int te = dir ? (TE_ - 1 - t) : t;
    float* hrd = hb + (t & 1) * 2048;
    float* hwr = hb + ((t & 1) ^ 1) * 2048;
    // hoist gin loads (plain, cross-kernel data) so latency overlaps staging
    float gpre[4] = {0, 0, 0, 0};
    if (tid < 64) {
#pragma unroll
      for (int gg = 0; gg < 4; ++gg)
        gpre[gg] = gin[((size_t)te * 8 + ub) * H4_ + gg * H_ + c0 + uhc];
    }
    // batched coherent staging of h-state (8 floats/thread = 2 x dwordx4)
    {
      float4 v0, v1;
      const float* a0 = &hrd[tid * 8];
      const float* a1 = &hrd[tid * 8 + 4];
      asm volatile(
          "global_load_dwordx4 %0, %2, off sc0 sc1\n\t"
          "global_load_dwordx4 %1, %3, off sc0 sc1"
          : "=&v"(v0), "=&v"(v1) : "v"(a0), "v"(a1));
      WAIT_VM();
      *(float4*)&sm[tid * 8] = v0;
      *(float4*)&sm[tid * 8 + 4] = v1;
    }
    __syncthreads();
    float acc[8] = {0, 0, 0, 0, 0, 0, 0, 0};
#pragma unroll
    for (int kk = 0; kk < 32; ++kk) {
      float w = wreg[kk];
      const float* hp = &sm[(kg + kk * 8) * 8];
#pragma unroll
      for (int b = 0; b < 8; ++b) acc[b] += hp[b] * w;
    }
    float* part = sm + 2048;
    *(float4*)&part[(jl * 8 + kg) * 8]     = make_float4(acc[0], acc[1], acc[2], acc[3]);
    *(float4*)&part[(jl * 8 + kg) * 8 + 4] = make_float4(acc[4], acc[5], acc[6], acc[7]);
    __syncthreads();
    if (tid < 64) {
      float g[4];
#pragma unroll
      for (int gg = 0; gg < 4; ++gg) {
        float s = gpre[gg];
#pragma unroll
        for (int k2 = 0; k2 < 8; ++k2) s += part[((gg * 8 + uhc) * 8 + k2) * 8 + ub];
        g[gg] = s;
      }
      float ci = sigm(g[0]), cf = sigm(g[1]), cg = tanh_fast(g[2]), co = sigm(g[3]);
      c_reg = cf * c_reg + ci * cg;
      float hn = co * tanh_fast(c_reg);
      st_at(&hwr[(c0 + uhc) * 8 + ub], hn);
      eo[((size_t)ub * TE_ + te) * H2_ + dir * H_ + c0 + uhc] = hn;
      if (t == TE_ - 1) cT[ub * H2_ + dir * H_ + c0 + uhc] = c_reg;
    }
    ep++; flag_bar(flg, 32, slot, ep);
  }
}

// =====================================================================
// K3: enc_feat = enc_out(3200,512) @ Wenc_feat(512,612) + benc_feat
// =====================================================================
__global__ __launch_bounds__(256) void k3_encfeat(
    const float* __restrict__ eo, const float* __restrict__ Wef,
    const float* __restrict__ bef, float* __restrict__ ef)
{
  __shared__ float AsT[32 * 64];
  __shared__ float Wsh[32 * 64];
  const int ct = blockIdx.x, rt = blockIdx.y, tid = threadIdx.x;
  const int c0 = ct * 64, r0 = rt * 64;
  const int tx = tid & 15, ty = tid >> 4;
  float4 acc0 = make_float4(0,0,0,0), acc1 = acc0, acc2 = acc0, acc3 = acc0;
  for (int kc = 0; kc < 16; ++kc) {
#pragma unroll
    for (int i = 0; i < 2; ++i) {
      int q = tid * 2 + i;
      int r = q >> 3, kq = q & 7;
      float4 v = *(const float4*)&eo[(size_t)(r0 + r) * H2_ + kc * 32 + kq * 4];
      AsT[(kq * 4 + 0) * 64 + r] = v.x; AsT[(kq * 4 + 1) * 64 + r] = v.y;
      AsT[(kq * 4 + 2) * 64 + r] = v.z; AsT[(kq * 4 + 3) * 64 + r] = v.w;
    }
#pragma unroll
    for (int i = 0; i < 2; ++i) {
      int q = tid * 2 + i;
      int kk = q >> 4, cq = q & 15;
      int col = c0 + cq * 4;
      float4 v = make_float4(0,0,0,0);
      if (col < A_) v = *(const float4*)&Wef[(size_t)(kc * 32 + kk) * A_ + col];
      *(float4*)&Wsh[kk * 64 + cq * 4] = v;
    }
    __syncthreads();
#pragma unroll
    for (int kk = 0; kk < 32; ++kk) {
      float4 w4 = *(float4*)&Wsh[kk * 64 + tx * 4];
      const float* ar = &AsT[kk * 64 + ty * 4];
      acc0.x += ar[0]*w4.x; acc0.y += ar[0]*w4.y; acc0.z += ar[0]*w4.z; acc0.w += ar[0]*w4.w;
      acc1.x += ar[1]*w4.x; acc1.y += ar[1]*w4.y; acc1.z += ar[1]*w4.z; acc1.w += ar[1]*w4.w;
      acc2.x += ar[2]*w4.x; acc2.y += ar[2]*w4.y; acc2.z += ar[2]*w4.z; acc2.w += ar[2]*w4.w;
      acc3.x += ar[3]*w4.x; acc3.y += ar[3]*w4.y; acc3.z += ar[3]*w4.z; acc3.w += ar[3]*w4.w;
    }
    __syncthreads();
  }
  const int col = c0 + tx * 4;
  if (col < A_) {
    float4 bb = *(const float4*)&bef[col];
    float4 r4[4] = {acc0, acc1, acc2, acc3};
#pragma unroll
    for (int i = 0; i < 4; ++i) {
      int row = r0 + ty * 4 + i;
      float4 o = make_float4(r4[i].x + bb.x, r4[i].y + bb.y, r4[i].z + bb.z, r4[i].w + bb.w);
      *(float4*)&ef[(size_t)row * A_ + col] = o;
    }
  }
}

// =====================================================================
// K4: decoder — 4 phases/step, batched wide coherent staging everywhere
//   A (64 blk): gates K=768=[ctx;h] -> (h,c)
//   P2 (39 blk compute, 24 XCD-matched prefetch Wdf[t+1]): decf
//   P3 (64 blk = b x te-slice): e over full a
//   P4 (64 blk = b x d-slice): softmax + ctx
// =====================================================================
__global__ __launch_bounds__(256, 1) void k4_decoder(
    const float* __restrict__ maskp,
    const float* __restrict__ Wred, const float* __restrict__ bred,
    const float* __restrict__ Whh_d, const float* __restrict__ b_d,
    const float* __restrict__ Wdf, const float* __restrict__ bdf,
    const float* __restrict__ vvec, float* __restrict__ ws, float* __restrict__ dob)
{
  __shared__ float sm[9216];
  float* chc  = ws + OFS_CHC;
  float* ctx  = ws + OFS_CTX;
  float* decf = ws + OFS_DECF;
  float* eg   = ws + OFS_EG;
  float* att  = ws + OFS_ATT;
  const float* eo  = ws + OFS_EO;
  const float* efG = ws + OFS_EF;
  const float* hbf = ws + OFS_HBF;
  const float* hbb = ws + OFS_HBB;
  const float* cT  = ws + OFS_CT;
  unsigned* flg = (unsigned*)(ws + OFS_FLG) + 256;
  const float* Wcg  = dob + DO_WCG;
  const float* gdec = dob + DO_GDEC;
  float* ctxh = dob + DO_CTXH;
  float* hch  = dob + DO_HCH;
  const int bid = blockIdx.x, tid = threadIdx.x;
  unsigned ep = 0;

  // stationary gate weights: block owns 4 h-cols x 4 gates; K=768
  const int kg = tid & 15, jl = tid >> 4;
  const int jcol = (jl >> 2) * 256 + (bid << 2) + (jl & 3);
  float wreg[48];
#pragma unroll
  for (int kk = 0; kk < 48; ++kk) {
    int k = kg + (kk << 4);
    wreg[kk] = (k < H2_) ? Wcg[(size_t)k * H4_ + jcol]
                         : Whh_d[(size_t)(k - H2_) * H4_ + jcol];
  }
  const int uhc = tid >> 3, ub = tid & 7;   // update roles (tid<32)

  // ---------------- P0: h0/c0, ctx0=0, XCD-aware prefetch Wdf[0] ----------------
  if (bid < 32) {
    const int isC = bid >> 4;
    const int b = (bid >> 1) & 7, half = bid & 1;
    for (int i = tid; i < H2_; i += 256)
      sm[i] = isC ? cT[b * H2_ + i]
                  : (i < H_ ? hbf[i * 8 + b] : hbb[(i - H_) * 8 + b]);
    __syncthreads();
    const int col_l = tid & 127, ks = tid >> 7;
    float acc = 0.0f;
    for (int kk = 0; kk < 256; ++kk) {
      int k = ks * 256 + kk;
      acc += sm[k] * Wred[(size_t)k * H_ + half * 128 + col_l];
    }
    sm[512 + ks * 128 + col_l] = acc;
    __syncthreads();
    if (tid < 128) {
      float v2 = fmaxf(sm[512 + tid] + sm[640 + tid] + bred[half * 128 + tid], 0.0f);
      st_at(&chc[b * H2_ + isC * H_ + half * 128 + tid], v2);
    }
  } else {
    if (bid == 32)
      for (int i = tid; i < 4096; i += 256) st_at(&ctx[i], 0.0f);
    const int x = bid & 7, g4 = (bid - 32) >> 3;   // 4 row-groups of 128
    float dm = 0.0f;
    for (int idx = tid; idx < 128 * 20; idx += 256) {
      int r = idx / 20, rem = idx - r * 20;
      int cb = x + ((rem >> 2) << 3);
      int col = cb * 16 + ((rem & 3) << 2);
      if (col + 3 < A_) {
        float4 vx = *(const float4*)&Wdf[(size_t)(g4 * 128 + r) * A_ + col];
        dm += vx.x + vx.y + vx.z + vx.w;
      }
    }
    asm volatile("" :: "v"(dm));
  }
  ep++; flag_bar(flg, 64, bid, ep);

  float c_reg = 0.0f;
  if (tid < 32) c_reg = ld_at(&chc[ub * H2_ + H_ + (bid << 2) + uhc]);

  // ---------------- main loop: 4 phases/step ----------------
  for (int t = 0; t < TD_; ++t) {
    const int cur = t & 1, nxt = cur ^ 1;

    // ===== A: g = gdec[t] + [ctx;h]@[Wcg;Whh_d] -> (h,c) =====
    {
      float gpre = 0.0f;
      if (tid < 128) {
        int jj = tid >> 3, b = tid & 7;
        int jc = (jj >> 2) * 256 + (bid << 2) + (jj & 3);
        gpre = gdec[((size_t)t * 8 + b) * H4_ + jc];
      }
      // batched coherent staging: 6 x dwordx4 per thread -> sm[k*9+b], k<768
      {
        float4 v0, v1, v2, v3, v4, v5;
        const float* ap[6];
        int kk0[6], bb[6];
#pragma unroll
        for (int i = 0; i < 6; ++i) {
          int f = tid + (i << 8);
          int b = f / 192, q = f - b * 192;
          bb[i] = b;
          kk0[i] = (q < 128) ? (q << 2) : (512 + ((q - 128) << 2));
          ap[i] = (q < 128) ? &ctx[b * H2_ + (q << 2)]
                            : &chc[cur * 4096 + b * H2_ + ((q - 128) << 2)];
        }
        asm volatile(
            "global_load_dwordx4 %0, %6, off sc0 sc1\n\t"
            "global_load_dwordx4 %1, %7, off sc0 sc1\n\t"
            "global_load_dwordx4 %2, %8, off sc0 sc1\n\t"
            "global_load_dwordx4 %3, %9, off sc0 sc1\n\t"
            "global_load_dwordx4 %4, %10, off sc0 sc1\n\t"
            "global_load_dwordx4 %5, %11, off sc0 sc1"
            : "=&v"(v0), "=&v"(v1), "=&v"(v2), "=&v"(v3), "=&v"(v4), "=&v"(v5)
            : "v"(ap[0]), "v"(ap[1]), "v"(ap[2]), "v"(ap[3]), "v"(ap[4]), "v"(ap[5]));
        WAIT_VM();
        float4 vv[6] = {v0, v1, v2, v3, v4, v5};
#pragma unroll
        for (int i = 0; i < 6; ++i) {
          sm[(kk0[i] + 0) * 9 + bb[i]] = vv[i].x;
          sm[(kk0[i] + 1) * 9 + bb[i]] = vv[i].y;
          sm[(kk0[i] + 2) * 9 + bb[i]] = vv[i].z;
          sm[(kk0[i] + 3) * 9 + bb[i]] = vv[i].w;
        }
      }
      __syncthreads();
      float acc[8] = {0, 0, 0, 0, 0, 0, 0, 0};
#pragma unroll
      for (int kk = 0; kk < 48; ++kk) {
        float w = wreg[kk];
        const float* hp = &sm[(kg + (kk << 4)) * 9];
#pragma unroll
        for (int b = 0; b < 8; ++b) acc[b] += hp[b] * w;
      }
      float* part = sm + 6912;
      *(float4*)&part[((jl << 4) + kg) * 8]     = make_float4(acc[0], acc[1], acc[2], acc[3]);
      *(float4*)&part[((jl << 4) + kg) * 8 + 4] = make_float4(acc[4], acc[5], acc[6], acc[7]);
      __syncthreads();
      float* g_l = sm + 8960;
      if (tid < 128) {
        int jj = tid >> 3, b = tid & 7;
        float s = gpre;
#pragma unroll
        for (int k2 = 0; k2 < 16; ++k2) s += part[((jj << 4) + k2) * 8 + b];
        g_l[jj * 8 + b] = s;
      }
      __syncthreads();
      if (tid < 32) {
        float g0 = g_l[(0 + uhc) * 8 + ub], g1 = g_l[(4 + uhc) * 8 + ub],
              g2 = g_l[(8 + uhc) * 8 + ub], g3 = g_l[(12 + uhc) * 8 + ub];
        float ci = sigm(g0), cf = sigm(g1), cg = tanh_fast(g2), co = sigm(g3);
        c_reg = cf * c_reg + ci * cg;
        float hn = co * tanh_fast(c_reg);
        int hc = (bid << 2) + uhc;
        float* hb2 = &chc[nxt * 4096 + ub * H2_];
        st_at(&hb2[hc], hn);
        st_at(&hb2[H_ + hc], c_reg);
        hch[((size_t)t * 8 + ub) * H2_ + hc] = hn;
        hch[((size_t)t * 8 + ub) * H2_ + H_ + hc] = c_reg;
      }
    }
    ep++; flag_bar(flg, 64, bid, ep);

    // ===== P2: decf = [h;c]@Wdf[t] + bdf[t] (blocks 0..38); 40..63 prefetch t+1 =====
    if (bid < 39) {
      // batched coherent staging of hc (4 x dwordx4 per thread) -> sm[k*8+b]
      {
        float4 v0, v1, v2, v3;
        const float* ap[4];
        int bb[4], qq[4];
#pragma unroll
        for (int i = 0; i < 4; ++i) {
          int f = tid + (i << 8);
          bb[i] = f >> 7; qq[i] = f & 127;
          ap[i] = &chc[nxt * 4096 + bb[i] * H2_ + (qq[i] << 2)];
        }
        asm volatile(
            "global_load_dwordx4 %0, %4, off sc0 sc1\n\t"
            "global_load_dwordx4 %1, %5, off sc0 sc1\n\t"
            "global_load_dwordx4 %2, %6, off sc0 sc1\n\t"
            "global_load_dwordx4 %3, %7, off sc0 sc1"
            : "=&v"(v0), "=&v"(v1), "=&v"(v2), "=&v"(v3)
            : "v"(ap[0]), "v"(ap[1]), "v"(ap[2]), "v"(ap[3]));
        WAIT_VM();
        float4 vv[4] = {v0, v1, v2, v3};
#pragma unroll
        for (int i = 0; i < 4; ++i) {
          int k0 = qq[i] << 2, b = bb[i];
          sm[(k0 + 0) * 8 + b] = vv[i].x;
          sm[(k0 + 1) * 8 + b] = vv[i].y;
          sm[(k0 + 2) * 8 + b] = vv[i].z;
          sm[(k0 + 3) * 8 + b] = vv[i].w;
        }
      }
      __syncthreads();
      const int a_l = tid & 15, ks = tid >> 4;
      const int a = bid * 16 + a_l;
      const bool va = a < A_;
      const float* wp = Wdf + (size_t)t * H2_ * A_;
      float acc[8] = {0, 0, 0, 0, 0, 0, 0, 0};
#pragma unroll 16
      for (int kk = 0; kk < 32; ++kk) {
        int k = (ks << 5) + kk;
        float w = va ? wp[(size_t)k * A_ + a] : 0.0f;
        const float* hp = &sm[k * 8];
#pragma unroll
        for (int b = 0; b < 8; ++b) acc[b] += w * hp[b];
      }
      float* part = sm + 4096;
      *(float4*)&part[((a_l << 4) + ks) * 8]     = make_float4(acc[0], acc[1], acc[2], acc[3]);
      *(float4*)&part[((a_l << 4) + ks) * 8 + 4] = make_float4(acc[4], acc[5], acc[6], acc[7]);
      __syncthreads();
      if (tid < 128) {
        const int a2l = tid >> 3, b2 = tid & 7;
        const int a2 = bid * 16 + a2l;
        if (a2 < A_) {
          float s = bdf[t * A_ + a2];
#pragma unroll
          for (int k2 = 0; k2 < 16; ++k2) s += part[((a2l << 4) + k2) * 8 + b2];
          st_at(&decf[b2 * A_ + a2], s);
        }
      }
    } else if (bid >= 40 && t + 1 < TD_) {
      // XCD-matched prefetch of Wdf[t+1]: XCD x serves compute blocks {x,x+8,..,x+32}
      const int x = bid & 7, g3 = (bid - 40) >> 3;     // 3 row-groups
      const int r0p = g3 * 171, nr = (g3 < 2) ? 171 : 170;
      const float* wp = Wdf + (size_t)(t + 1) * H2_ * A_;
      float dm = 0.0f;
      for (int idx = tid; idx < nr * 20; idx += 256) {
        int r = idx / 20, rem = idx - r * 20;
        int cb = x + ((rem >> 2) << 3);
        int col = cb * 16 + ((rem & 3) << 2);
        if (col + 3 < A_) {
          float4 vx = *(const float4*)&wp[(size_t)(r0p + r) * A_ + col];
          dm += vx.x + vx.y + vx.z + vx.w;
        }
      }
      asm volatile("" :: "v"(dm));
    }
    ep++; flag_bar(flg, 64, bid, ep);

    // ===== P3: e[b][te] = sum_a v[a]*tanh(enc_feat + dec_feat) =====
    {
      const int b = bid >> 3, te0 = (bid & 7) * 50;
      float* dfl = sm;            // 612
      float* vvl = sm + 640;      // 612
      float* pe  = sm + 1280;     // [50][5]
      {
        float4 dv;
        const float* ap0 = &decf[b * A_ + ((tid < 153 ? tid : 152) << 2)];
        asm volatile("global_load_dwordx4 %0, %1, off sc0 sc1" : "=&v"(dv) : "v"(ap0));
        WAIT_VM();
        if (tid < 153) {
          dfl[(tid << 2) + 0] = dv.x; dfl[(tid << 2) + 1] = dv.y;
          dfl[(tid << 2) + 2] = dv.z; dfl[(tid << 2) + 3] = dv.w;
        }
      }
      for (int i = tid; i < A_; i += 256) vvl[i] = vvec[i];
      __syncthreads();
      if (tid < 250) {
        const int te_l = tid % 50, ks2 = tid / 50;
        const int k0 = ks2 * 128;
        const int kend = (k0 + 128 < A_) ? k0 + 128 : A_;
        const float* efp = &efG[(size_t)(b * TE_ + te0 + te_l) * A_];
        float acc = 0.0f;
        for (int k = k0; k < kend; k += 4) {
          float4 e4 = *(const float4*)&efp[k];
          float4 d4 = *(const float4*)&dfl[k];
          float4 v4 = *(const float4*)&vvl[k];
          acc += v4.x * tanh_fast(e4.x + d4.x);
          acc += v4.y * tanh_fast(e4.y + d4.y);
          acc += v4.z * tanh_fast(e4.z + d4.z);
          acc += v4.w * tanh_fast(e4.w + d4.w);
        }
        pe[te_l * 5 + ks2] = acc;
      }
      __syncthreads();
      if (tid < 50)
        st_at(&eg[b * TE_ + te0 + tid],
              pe[tid * 5] + pe[tid * 5 + 1] + pe[tid * 5 + 2] + pe[tid * 5 + 3] + pe[tid * 5 + 4]);
    }
    ep++; flag_bar(flg, 64, bid, ep);

    // ===== P4: softmax(+mask, renorm), ctx =====
    {
      const int b = bid >> 3, d0 = (bid & 7) * 64;
      float* eu  = sm;            // 400
      float* red = sm + 512;      // 256
      float* pc  = sm + 800;      // 256
      {
        float4 ev;
        const float* ap0 = &eg[b * TE_ + ((tid < 100 ? tid : 99) << 2)];
        asm volatile("global_load_dwordx4 %0, %1, off sc0 sc1" : "=&v"(ev) : "v"(ap0));
        WAIT_VM();
        if (tid < 100) {
          eu[(tid << 2) + 0] = ev.x; eu[(tid << 2) + 1] = ev.y;
          eu[(tid << 2) + 2] = ev.z; eu[(tid << 2) + 3] = ev.w;
        }
      }
      __syncthreads();
      float m = -3.4e38f;
      for (int i = tid; i < TE_; i += 256) m = fmaxf(m, eu[i]);
      red[tid] = m; __syncthreads();
      for (int s2 = 128; s2 > 0; s2 >>= 1) { if (tid < s2) red[tid] = fmaxf(red[tid], red[tid + s2]); __syncthreads(); }
      m = red[0]; __syncthreads();
      float sl = 0.0f;
      for (int i = tid; i < TE_; i += 256) {
        float u = __expf(eu[i] - m) * maskp[b * TE_ + i];
        eu[i] = u; sl += u;
      }
      red[tid] = sl; __syncthreads();
      for (int s2 = 128; s2 > 0; s2 >>= 1) { if (tid < s2) red[tid] += red[tid + s2]; __syncthreads(); }
      const float inv = rcp_fast(red[0]);
      const int d_l = tid & 63, ts = tid >> 6;
      float acc = 0.0f;
      for (int i = 0; i < 100; ++i) {
        int te = ts * 100 + i;
        acc += eu[te] * eo[(size_t)(b * TE_ + te) * H2_ + d0 + d_l];
      }
      pc[ts * 64 + d_l] = acc;
      __syncthreads();
      if (tid < 64) {
        float cv = (pc[tid] + pc[64 + tid] + pc[128 + tid] + pc[192 + tid]) * inv;
        st_at(&ctx[b * H2_ + d0 + tid], cv);
        ctxh[((size_t)t * 8 + b) * H2_ + d0 + tid] = cv;
      }
      if ((bid & 7) == 0)
        for (int i = tid; i < TE_; i += 256) att[((size_t)t * 8 + b) * TE_ + i] = eu[i] * inv;
    }
    ep++; flag_bar(flg, 64, bid, ep);
  }
}

// =====================================================================
// K4b: batched post-pass: x_t, outs_t, p_gen_t for all t (grid 100)
// =====================================================================
__global__ __launch_bounds__(256) void k4b_post(
    const float* __restrict__ Wx, const float* __restrict__ Wout, const float* __restrict__ bout,
    const float* __restrict__ Wpg, const float* __restrict__ bpg,
    float* __restrict__ ws, const float* __restrict__ dob)
{
  __shared__ float hcl[4096], ctxl[4096], cpl[4096], xl[1024], red2[256];
  const int t = blockIdx.x, tid = threadIdx.x;
  const float* hch  = dob + DO_HCH;
  const float* ctxh = dob + DO_CTXH;
  const float* xpre = dob + DO_XPRE;
  for (int i = tid; i < 4096; i += 256) {
    hcl[i]  = hch[(size_t)t * 4096 + i];
    ctxl[i] = ctxh[(size_t)t * 4096 + i];
    cpl[i]  = t ? ctxh[(size_t)(t - 1) * 4096 + i] : 0.0f;
  }
  __syncthreads();
  {
    const int col = tid & 127, bh = tid >> 7;
#pragma unroll
    for (int ii = 0; ii < 4; ++ii) {
      int b = bh + (ii << 1);
      float acc = xpre[(size_t)t * 1024 + b * E_ + col];
      for (int k = 0; k < H2_; ++k) acc += cpl[b * H2_ + k] * Wx[(size_t)(128 + k) * E_ + col];
      xl[b * E_ + col] = acc;
    }
  }
  __syncthreads();
  {
    const int col = tid;
    for (int b = 0; b < 8; ++b) {
      float acc = bout[col];
      for (int k = 0; k < 768; ++k)
        acc += (k < H_ ? hcl[b * H2_ + k] : ctxl[b * H2_ + (k - H_)]) * Wout[(size_t)k * H_ + col];
      ws[OFS_OUTS + ((size_t)t * 8 + b) * H_ + col] = acc;
    }
  }
  {
    const int b = tid >> 5, sg = tid & 31;
    float acc = 0.0f;
    for (int j = 0; j < 36; ++j) {
      int k = sg * 36 + j;
      float xv;
      if (k < H2_)       xv = ctxl[b * H2_ + k];
      else if (k < 768)  xv = hcl[b * H2_ + (k - H2_)];
      else if (k < 1024) xv = hcl[b * H2_ + H_ + (k - 768)];
      else               xv = xl[b * E_ + (k - 1024)];
      acc += xv * Wpg[k];
    }
    red2[tid] = acc;
    __syncthreads();
    if (tid < 8) {
      float s = 0.0f;
      for (int k2 = 0; k2 < 32; ++k2) s += red2[tid * 32 + k2];
      ws[OFS_PG + t * 8 + tid] = sigm(s + bpg[0]);
    }
  }
}

// =====================================================================
// K5a: logits = outs(800,256) @ Wv(256,50000) + bv -> d_out
// =====================================================================
__global__ __launch_bounds__(256) void k5a_logits(
    const float* __restrict__ outs, const float* __restrict__ Wv,
    const float* __restrict__ bv, float* __restrict__ out)
{
  __shared__ float aT[32 * 64];
  __shared__ float wl[32 * 256];
  const int ct = blockIdx.x, rt = blockIdx.y, tid = threadIdx.x;
  const int r0 = rt * 64, c0 = ct * 256;
  const int cq = tid & 63, rg = tid >> 6;
  float4 acc[16];
#pragma unroll
  for (int i = 0; i < 16; ++i) acc[i] = make_float4(0, 0, 0, 0);
  for (int kc = 0; kc < 8; ++kc) {
#pragma unroll
    for (int i = 0; i < 2; ++i) {
      int q = tid * 2 + i;
      int r = q >> 3, kq = q & 7;
      float4 v = make_float4(0, 0, 0, 0);
      if (r0 + r < 800) v = *(const float4*)&outs[(size_t)(r0 + r) * H_ + kc * 32 + kq * 4];
      aT[(kq * 4 + 0) * 64 + r] = v.x; aT[(kq * 4 + 1) * 64 + r] = v.y;
      aT[(kq * 4 + 2) * 64 + r] = v.z; aT[(kq * 4 + 3) * 64 + r] = v.w;
    }
#pragma unroll
    for (int i = 0; i < 8; ++i) {
      int q = tid + i * 256;
      int kk = q >> 6, c4 = q & 63;
      int col = c0 + c4 * 4;
      float4 v = make_float4(0, 0, 0, 0);
      if (col < V_) v = *(const float4*)&Wv[(size_t)(kc * 32 + kk) * V_ + col];
      *(float4*)&wl[kk * 256 + c4 * 4] = v;
    }
    __syncthreads();
#pragma unroll
    for (int kk = 0; kk < 32; ++kk) {
      float4 w4 = *(float4*)&wl[kk * 256 + cq * 4];
      const float* ar = &aT[kk * 64 + rg * 16];
#pragma unroll
      for (int rr = 0; rr < 16; ++rr) {
        float a = ar[rr];
        acc[rr].x += a * w4.x; acc[rr].y += a * w4.y;
        acc[rr].z += a * w4.z; acc[rr].w += a * w4.w;
      }
    }
    __syncthreads();
  }
  const int col = c0 + cq * 4;
  if (col < V_) {
    float4 bb = *(const float4*)&bv[col];
#pragma unroll
    for (int rr = 0; rr < 16; ++rr) {
      int row = r0 + rg * 16 + rr;
      if (row < 800) {
        float2 lo = make_float2(acc[rr].x + bb.x, acc[rr].y + bb.y);
        float2 hi = make_float2(acc[rr].z + bb.z, acc[rr].w + bb.w);
        *(float2*)&out[(size_t)row * VEXT_ + col] = lo;
        *(float2*)&out[(size_t)row * VEXT_ + col + 2] = hi;
      }
    }
  }
}

// K5b: per-row sum of exp(logit)
__global__ __launch_bounds__(256) void k5b_rowsum(const float* __restrict__ out, float* __restrict__ Srow)
{
  __shared__ float red[256];
  const int r = blockIdx.x, tid = threadIdx.x;
  const float* base = out + (size_t)r * VEXT_;
  float s = 0.0f;
  for (int i = tid; i < V_ / 2; i += 256) {
    float2 v = *(const float2*)&base[i * 2];
    s += __expf(v.x) + __expf(v.y);
  }
  red[tid] = s; __syncthreads();
  for (int st = 128; st > 0; st >>= 1) { if (tid < st) red[tid] += red[tid + st]; __syncthreads(); }
  if (tid == 0) Srow[r] = red[0];
}

// K5c: in-place final = pgen * exp(logit)/S ; zero OOV tail
__global__ __launch_bounds__(256) void k5c_final(
    float* __restrict__ out, const float* __restrict__ Srow, const float* __restrict__ pg)
{
  const int cc = blockIdx.x, r = blockIdx.y, tid = threadIdx.x;
  const float scale = pg[r] * rcp_fast(Srow[r]);
  float* base = out + (size_t)r * VEXT_;
#pragma unroll
  for (int i = 0; i < 4; ++i) {
    int col = cc * 2048 + i * 512 + tid * 2;
    if (col < V_) {
      float2 v = *(float2*)&base[col];
      v.x = __expf(v.x) * scale; v.y = __expf(v.y) * scale;
      *(float2*)&base[col] = v;
    } else if (col < VEXT_) {
      *(float2*)&base[col] = make_float2(0.0f, 0.0f);
    }
  }
}

// K5d: scatter copy distribution
__global__ __launch_bounds__(256) void k5d_scatter(
    float* __restrict__ out, const float* __restrict__ ws, const int* __restrict__ ext)
{
  const int r = blockIdx.x, tid = threadIdx.x;
  const int b = r & 7;
  const float* at = ws + OFS_ATT + (size_t)r * TE_;
  const float w = 1.0f - ws[OFS_PG + r];
  float* base = out + (size_t)r * VEXT_;
  for (int i = tid; i < TE_; i += 256)
    atomicAdd(&base[ext[b * TE_ + i]], w * at[i]);
}

// =====================================================================
extern "C" void kernel_launch(void* const* d_in, const int* in_sizes, int n_in,
                              void* d_out, int out_size, void* d_ws, size_t ws_size,
                              hipStream_t stream) {
  const int*   etok  = (const int*)d_in[0];
  const int*   dtok  = (const int*)d_in[1];
  const int*   ext   = (const int*)d_in[2];
  const float* maskp = (const float*)d_in[3];
  const float* emb   = (const float*)d_in[4];
  const float* Wih_f = (const float*)d_in[5];
  const float* Whh_f = (const float*)d_in[6];
  const float* b_f   = (const float*)d_in[7];
  const float* Wih_b = (const float*)d_in[8];
  const float* Whh_b = (const float*)d_in[9];
  const float* b_b   = (const float*)d_in[10];
  const float* Wred  = (const float*)d_in[11];
  const float* bred  = (const float*)d_in[12];
  const float* Wef   = (const float*)d_in[13];
  const float* bef   = (const float*)d_in[14];
  const float* vvec  = (const float*)d_in[15];
  const float* Wx    = (const float*)d_in[16];
  const float* bx    = (const float*)d_in[17];
  const float* Wih_d = (const float*)d_in[18];
  const float* Whh_d = (const float*)d_in[19];
  const float* b_d   = (const float*)d_in[20];
  const float* Wdf   = (const float*)d_in[21];
  const float* bdf   = (const float*)d_in[22];
  const float* Wpg   = (const float*)d_in[23];
  const float* bpg   = (const float*)d_in[24];
  const float* Wout  = (const float*)d_in[25];
  const float* bout  = (const float*)d_in[26];
  const float* Wv    = (const float*)d_in[27];
  const float* bv    = (const float*)d_in[28];
  float* out = (float*)d_out;
  float* wsf = (float*)d_ws;
  float* dob = out;   // d_out used as scratch until k5a overwrites it

  float* gin_f = dob + DO_GINF;
  float* gin_b = dob + DO_GINB;

  k1_embed_gates<<<400, 256, 0, stream>>>(etok, emb, Wih_f, b_f, Wih_b, b_b, gin_f, gin_b, wsf);
  k0_wcg<<<dim3(16, 8), 256, 0, stream>>>(Wx, Wih_d, dob);
  k1d_dec_pre<<<100, 256, 0, stream>>>(dtok, emb, Wx, bx, Wih_d, b_d, dob);

  {
    void* args2[5] = {(void*)&gin_f, (void*)&gin_b, (void*)&Whh_f, (void*)&Whh_b, (void*)&wsf};
    if (hipLaunchCooperativeKernel((void*)k2_encoder_scan, dim3(64), dim3(256), args2, 0, stream) != hipSuccess)
      k2_encoder_scan<<<64, 256, 0, stream>>>(gin_f, gin_b, Whh_f, Whh_b, wsf);
  }

  k3_encfeat<<<dim3(10, 50), 256, 0, stream>>>(wsf + OFS_EO, Wef, bef, wsf + OFS_EF);

  {
    void* args4[10] = {(void*)&maskp, (void*)&Wred, (void*)&bred, (void*)&Whh_d, (void*)&b_d,
                       (void*)&Wdf, (void*)&bdf, (void*)&vvec, (void*)&wsf, (void*)&dob};
    if (hipLaunchCooperativeKernel((void*)k4_decoder, dim3(64), dim3(256), args4, 0, stream) != hipSuccess)
      k4_decoder<<<64, 256, 0, stream>>>(maskp, Wred, bred, Whh_d, b_d, Wdf, bdf, vvec, wsf, dob);
  }

  k4b_post<<<100, 256, 0, stream>>>(Wx, Wout, bout, Wpg, bpg, wsf, dob);

  k5a_logits<<<dim3(196, 13), 256, 0, stream>>>(wsf + OFS_OUTS, Wv, bv, out);
  k5b_rowsum<<<800, 256, 0, stream>>>(out, wsf + OFS_SROW);
  k5c_final<<<dim3(25, 800), 256, 0, stream>>>(out, wsf + OFS_SROW, wsf + OFS_PG);
  k5d_scatter<<<800, 256, 0, stream>>>(out, wsf, ext);
}